// Round 11
// baseline (339.705 us; speedup 1.0000x reference)
//
#include <hip/hip_runtime.h>

// B=4, T=4096, D=1024. Inputs/outputs fp32. GEMM in bf16 MFMA.
// Pipeline: ln_conv -> gemm1 (+fused per-chunk scan aggregates) -> combine -> final -> gemm2.
// Numerics: la = log(alpha+1e-8) <= ~1e-8, so global max of cumsum ~= la[t=0] (error <= 4e-5);
// m is read from la row t=0 in combine; no max machinery anywhere.
// R11: BARRIER-FREE GEMM. Six lockstep structures all plateaued at MfmaUtil 17%; the shared
//     property was block-wide s_barrier phases (no cross-phase overlap, compiler pinned).
//     Now: 8 independent waves per block, each a private 64x128 pipeline: A in wave-private
//     LDS (2x4KB, gload_lds, depth-2), B direct global->reg (L1-resident 8KB tile shared by
//     all waves), ZERO s_barrier. Per-iter WAITVM(4): FIFO-newest-4 are always subset of
//     {B(t-1), STGA(t+1)}, both issued after STGA(t) => A(t) landed (steady state + tails,
//     no special cases). lgkmcnt(0) orders wave-local ds_reads before same-buffer overwrite.
//     Same per-acc MFMA order (ascending 32-K-chunks) -> bit-identical; canary 0.109375.
#define D_DIM 1024
#define B_DIM 4
#define T_DIM 4096
#define M_DIM (B_DIM * T_DIM)   // 16384 rows
#define CHUNK 32
#define NCHUNK (T_DIM / CHUNK)  // 128
#define NWAVE_C 16              // waves per combine block
#define SEG (NCHUNK / NWAVE_C)  // 8 chunks per wave in combine
#define NKT (D_DIM / 32)        // 32 K-tiles of 32

typedef unsigned short u16;
typedef __attribute__((ext_vector_type(8))) __bf16 bf16x8;
typedef __attribute__((ext_vector_type(4))) float f32x4;

__device__ __forceinline__ float bf2f(u16 u) {
    union { unsigned int i; float f; } v;
    v.i = ((unsigned int)u) << 16;
    return v.f;
}
__device__ __forceinline__ u16 f2bf(float f) {
    union { float f; unsigned int i; } v;
    v.f = f;
    unsigned int u = v.i;
    unsigned int r = (u + 0x7fffu + ((u >> 16) & 1u)) >> 16;
    return (u16)r;
}
__device__ __forceinline__ float fast_tanh(float v) {
    float e = __expf(2.f * v);
    return 1.f - 2.f / (e + 1.f);
}

#define GLOAD16(g, l)                                                   \
    __builtin_amdgcn_global_load_lds(                                   \
        (const __attribute__((address_space(1))) void*)(g),             \
        (__attribute__((address_space(3))) void*)(l), 16, 0, 0)

#define WAITVM(N) asm volatile("s_waitcnt vmcnt(" #N ")" ::: "memory")
#define WAITLGKM0() asm volatile("s_waitcnt lgkmcnt(0)" ::: "memory")

// ---------------- fused weight-convert (blocks 0..2047) + wave-per-row LayerNorm ----------
__global__ __launch_bounds__(256) void ln_conv_kernel(const float* __restrict__ x,
                                                      const float* __restrict__ w,
                                                      const float* __restrict__ b,
                                                      u16* __restrict__ xn,
                                                      const float* __restrict__ Wf,
                                                      const float* __restrict__ Wr,
                                                      u16* __restrict__ da,
                                                      u16* __restrict__ db) {
    int tid = threadIdx.x;
    if (blockIdx.x < 2048) {            // convert: 2 x 262144 float4s
        int i = blockIdx.x * 256 + tid;
        const float* s = (i < 262144) ? Wf : Wr;
        u16* dp = (i < 262144) ? da : db;
        int j = i & 262143;
        float4 v = ((const float4*)s)[j];
        ushort4 o;
        o.x = f2bf(v.x); o.y = f2bf(v.y); o.z = f2bf(v.z); o.w = f2bf(v.w);
        ((ushort4*)dp)[j] = o;
        return;
    }
    // LN: one wave per row, 4 rows per block, no __syncthreads
    int wv = tid >> 6, lane = tid & 63;
    int row = (blockIdx.x - 2048) * 4 + wv;
    const float4* xr = (const float4*)(x + (size_t)row * D_DIM);
    float4 xv[4];
    #pragma unroll
    for (int k = 0; k < 4; k++) xv[k] = xr[lane + 64 * k];
    float s = 0.f, s2 = 0.f;
    #pragma unroll
    for (int k = 0; k < 4; k++) {
        s  += xv[k].x + xv[k].y + xv[k].z + xv[k].w;
        s2 += xv[k].x * xv[k].x + xv[k].y * xv[k].y
            + xv[k].z * xv[k].z + xv[k].w * xv[k].w;
    }
    #pragma unroll
    for (int o = 1; o < 64; o <<= 1) {
        s  += __shfl_xor(s, o, 64);
        s2 += __shfl_xor(s2, o, 64);
    }
    float mu = s * (1.0f / D_DIM);
    float var = s2 * (1.0f / D_DIM) - mu * mu;
    float rs = rsqrtf(var + 1e-5f);
    ushort4* xo = (ushort4*)(xn + (size_t)row * D_DIM);
    #pragma unroll
    for (int k = 0; k < 4; k++) {
        float4 wv4 = ((const float4*)w)[lane + 64 * k];
        float4 bv4 = ((const float4*)b)[lane + 64 * k];
        ushort4 o;
        o.x = f2bf((xv[k].x - mu) * rs * wv4.x + bv4.x);
        o.y = f2bf((xv[k].y - mu) * rs * wv4.y + bv4.y);
        o.z = f2bf((xv[k].z - mu) * rs * wv4.z + bv4.z);
        o.w = f2bf((xv[k].w - mu) * rs * wv4.w + bv4.w);
        xo[lane + 64 * k] = o;
    }
}

// ---------------- barrier-free 512x128 GEMM core: 8 independent 64x128 wave pipelines ----
// A [M][1024], B [N][1024] row-major bf16 (C = A.B^T slice).
// Per wave: A rows tile_m+wave*64..+63 in PRIVATE LDS (2 bufs x 4KB = 4096 u16 region;
//   staged 4x gload_lds/tile, 4-slot XOR swizzle slot^=(row&3) via pre-swizzled source);
//   B rows tile_n..+127 read direct global->reg (8x bf16x8/tile; lanes {f,f+16,f+32,f+48}
//   cover one 64B line; the 8KB B-tile is shared by all 8 waves -> L1 hits).
// Per iter t: WAITVM(4) [FIFO: newest<=4 in {B(t-1),STGA(t+1)}, all after STGA(t) =>
//   A(t) landed; also fences ds_read hoisting] -> 8 B loads -> 4 ds_read A -> lgkmcnt(0)
//   [reads retired before same-buffer overwrite; gload_lds can't cross the clobber] ->
//   STGA(t+2) -> 32 MFMA. NO s_barrier anywhere. Acc: one MFMA/acc per ascending K-chunk.
__device__ __forceinline__ void gemm_wave_core(const u16* __restrict__ AG,
                                               const u16* __restrict__ BG,
                                               int tile_m, int tile_n,
                                               u16* ldsWave,   // this wave's 4096-u16 region
                                               f32x4 (*acc)[8]) {
    int lane = threadIdx.x & 63;
    int wave = threadIdx.x >> 6;
    int fr = lane & 15, q = lane >> 4;
    // A staging: instr j covers rows wave*64 + j*16 + (lane>>2), 16B slot lane&3;
    // source col-slot pre-swizzled: (lane&3) ^ (row&3), row&3 == (lane>>2)&3.
    int lr = lane >> 2;
    const u16* gA = AG + (size_t)(tile_m + wave * 64 + lr) * D_DIM
                  + (((lane & 3) ^ (lr & 3)) * 8);
    // A fragment read: row mi*16+fr, LDS slot q^(fr&3) (swizzle cancels)
    const u16* pAb = ldsWave + fr * 32 + (q ^ (fr & 3)) * 8;
    // B: per-ni row tile_n + ni*16 + fr, k-slot q
    const u16* pB = BG + (size_t)(tile_n + fr) * D_DIM + q * 8;

#define STGA(tt)                                                            \
    do {                                                                    \
        _Pragma("unroll") for (int j = 0; j < 4; j++)                       \
            GLOAD16(gA + (size_t)j * (16 * D_DIM) + (size_t)(tt) * 32,      \
                    ldsWave + ((tt) & 1) * 2048 + j * 512);                 \
    } while (0)

    STGA(0);
    STGA(1);
    for (int t = 0; t < NKT; t++) {
        WAITVM(4);   // A(t) landed (see header proof); fences ds_read hoisting
        bf16x8 Bf[8];
        #pragma unroll
        for (int ni = 0; ni < 8; ni++)
            Bf[ni] = *(const bf16x8*)(pB + (size_t)ni * (16 * D_DIM) + (size_t)t * 32);
        const u16* pA = pAb + (t & 1) * 2048;
        bf16x8 Af[4];
        #pragma unroll
        for (int mi = 0; mi < 4; mi++) Af[mi] = *(const bf16x8*)(pA + mi * 512);
        WAITLGKM0();                     // wave-local: reads retired before overwrite
        if (t + 2 < NKT) STGA(t + 2);
        #pragma unroll
        for (int mi = 0; mi < 4; mi++)
            #pragma unroll
            for (int ni = 0; ni < 8; ni++)
                acc[mi][ni] = __builtin_amdgcn_mfma_f32_16x16x32_bf16(
                    Af[mi], Bf[ni], acc[mi][ni], 0, 0, 0);
    }
#undef STGA
}

// ---------------- GEMM1: alpha=sigmoid(xn@Wf^T+bf+ab); writes la (bf16) and, fused,
// per-chunk scan aggregates S = sum(la over 32 t), Tb = sum(bx*exp(local incl. cumsum)).
// Wave owns 64x128 = 2 chunks (mi pairs); prefix over q=lane>>4 via shfl_up as before.
__global__ __launch_bounds__(512, 2) void gemm1_kernel(const u16* __restrict__ xn,
                                                       const u16* __restrict__ Wfc,
                                                       const float* __restrict__ bf_,
                                                       const float* __restrict__ ab,
                                                       const float* __restrict__ bs,
                                                       u16* __restrict__ out_la,
                                                       float* __restrict__ Sg,
                                                       float* __restrict__ Tg) {
    __shared__ __align__(16) u16 lds[32768];   // 64 KiB: 8 waves x 4096 u16 private
    // bijective XCD chunking: 256 blocks = 8 XCD x (4 m-panels x 8 n-tiles)
    int flat = blockIdx.y * 8 + blockIdx.x;
    int xcd = flat & 7, p = flat >> 3;         // p in 0..31
    int tile_m = (xcd * 4 + (p & 3)) * 512;
    int tile_n = (p >> 2) * 128;
    int wave = threadIdx.x >> 6, lane = threadIdx.x & 63;
    f32x4 acc[4][8] = {};
    gemm_wave_core(xn, Wfc, tile_m, tile_n, lds + wave * 4096, acc);

    // epilogue: C/D layout col=lane&15 (+ni*16), row=(lane>>4)*4+r (+mi*16) [m89-verified]
    float abv = ab[0], bsv = bs[0];
    int q = lane >> 4, l = lane & 15;
    #pragma unroll
    for (int ni = 0; ni < 8; ni++) {
        int col = tile_n + ni * 16 + l;
        float bcol = bf_[col];
        #pragma unroll
        for (int ch = 0; ch < 2; ch++) {   // chunk (32 rows) = mi pair {2ch, 2ch+1}
            float lav[2][4], bxv[2][4];
            #pragma unroll
            for (int h = 0; h < 2; h++) {
                int mi = 2 * ch + h;
                #pragma unroll
                for (int r = 0; r < 4; r++) {
                    int row = tile_m + wave * 64 + mi * 16 + q * 4 + r;
                    float z = acc[mi][ni][r] + bcol + abv;
                    float alpha = 1.f / (1.f + __expf(-z));
                    float la_ = __logf(alpha + 1e-8f);
                    float xv = bf2f(xn[(size_t)row * D_DIM + col]);
                    lav[h][r] = la_;
                    bxv[h][r] = bsv * (1.f - alpha) * xv;
                    out_la[(size_t)row * D_DIM + col] = f2bf(la_);
                }
            }
            // wave-local chunk scan: t = h*16 + q*4 + r
            float s0 = lav[0][0] + lav[0][1] + lav[0][2] + lav[0][3];
            float s1 = lav[1][0] + lav[1][1] + lav[1][2] + lav[1][3];
            float x0 = s0, x1 = s1, y;
            y = __shfl_up(x0, 16, 64); if (q >= 1) x0 += y;
            y = __shfl_up(x0, 32, 64); if (q >= 2) x0 += y;
            y = __shfl_up(x1, 16, 64); if (q >= 1) x1 += y;
            y = __shfl_up(x1, 32, 64); if (q >= 2) x1 += y;
            float t0 = __shfl(x0, l + 48, 64);   // totals from q=3 lane
            float t1 = __shfl(x1, l + 48, 64);
            float e0 = x0 - s0, e1 = x1 - s1;    // exclusive prefixes over q
            float pr = e0, Tp = 0.f;
            #pragma unroll
            for (int r = 0; r < 4; r++) { pr += lav[0][r]; Tp += bxv[0][r] * __expf(pr); }
            pr = t0 + e1;
            #pragma unroll
            for (int r = 0; r < 4; r++) { pr += lav[1][r]; Tp += bxv[1][r] * __expf(pr); }
            Tp += __shfl_xor(Tp, 16, 64);
            Tp += __shfl_xor(Tp, 32, 64);
            if (q == 0) {
                int cidx = ((tile_m + wave * 64) >> 5) + ch;   // = b*NCHUNK + chunk
                Sg[(size_t)cidx * D_DIM + col] = t0 + t1;
                Tg[(size_t)cidx * D_DIM + col] = Tp;
            }
        }
    }
}

// ---------------- combine: per (b,d), prefix over 128 chunks. m = la[b, t=0, d]. ----------
__global__ __launch_bounds__(1024) void scan_combine(const u16* __restrict__ la,
                                                     const float* __restrict__ S,
                                                     const float* __restrict__ Tb,
                                                     float* __restrict__ Of,
                                                     float* __restrict__ SSp) {
    __shared__ float lsS[NWAVE_C][64], lsW[NWAVE_C][64];
    int b = blockIdx.x >> 4;
    int dg = blockIdx.x & 15;
    int wave = threadIdx.x >> 6, lane = threadIdx.x & 63;
    int d = dg * 64 + lane;
    float m = bf2f(la[(size_t)(b * T_DIM) * D_DIM + d]);   // cumsum[0] ~= global max
    size_t base = ((size_t)b * NCHUNK) * D_DIM + d;
    int c0 = wave * SEG;

    float OfR[SEG], wR[SEG];
    float Or = 0.f, w = 0.f;
    #pragma unroll
    for (int j = 0; j < SEG; j++) {
        size_t ci = base + (size_t)(c0 + j) * D_DIM;
        OfR[j] = Or;
        wR[j]  = w;
        w  += __expf(Or) * Tb[ci];
        Or += S[ci];
    }
    lsS[wave][lane] = Or; lsW[wave][lane] = w;
    __syncthreads();

    float o = 0.f, s = 0.f, myO = 0.f, myS = 0.f;
    #pragma unroll
    for (int w2 = 0; w2 < NWAVE_C; w2++) {
        if (w2 == wave) { myO = o; myS = s; }
        s += __expf(o - m) * lsW[w2][lane];
        o += lsS[w2][lane];
    }

    float em = __expf(myO - m);
    #pragma unroll
    for (int j = 0; j < SEG; j++) {
        size_t ci = base + (size_t)(c0 + j) * D_DIM;
        Of[ci]  = myO + OfR[j] - m;
        SSp[ci] = myS + em * wR[j];
    }
}

// ---------------- final: scale=exp(Of+p), s_star=SSp+cumsum, out=s_star/(scale+1e-8) -----
// 4 cols/thread; osc aliases xn (reads at idx precede the write at idx, same thread).
__global__ __launch_bounds__(256) void scan_final(const u16* __restrict__ la,
                                                  const u16* __restrict__ xn,
                                                  const float* __restrict__ bs,
                                                  const float* __restrict__ Of,
                                                  const float* __restrict__ SSp,
                                                  u16* __restrict__ osc) {
    int bc = blockIdx.x;
    int b = bc >> 7, c = bc & (NCHUNK - 1);
    int col0 = threadIdx.x * 4;
    float bsv = bs[0];
    size_t base = ((size_t)(b * T_DIM + c * CHUNK)) * D_DIM + col0;
    size_t ci = ((size_t)(b * NCHUNK + c)) * D_DIM + col0;
    float ofs[4], ss[4], p[4];
    #pragma unroll
    for (int j = 0; j < 4; j++) { ofs[j] = Of[ci + j]; ss[j] = SSp[ci + j]; p[j] = 0.f; }
    #pragma unroll 8
    for (int t = 0; t < CHUNK; t++) {
        size_t idx = base + (size_t)t * D_DIM;
        ushort4 lv = *(const ushort4*)(la + idx);
        ushort4 xv = *(const ushort4*)(xn + idx);
        u16 lvs[4] = {lv.x, lv.y, lv.z, lv.w};
        u16 xvs[4] = {xv.x, xv.y, xv.z, xv.w};
        u16 os[4];
        #pragma unroll
        for (int j = 0; j < 4; j++) {
            float lav = bf2f(lvs[j]);
            p[j] += lav;
            float scv = __expf(ofs[j] + p[j]);
            float bx = bsv * (1.f - __expf(lav)) * bf2f(xvs[j]);
            ss[j] += bx * scv;
            os[j] = f2bf(ss[j] / (scv + 1e-8f));
        }
        ushort4 o; o.x = os[0]; o.y = os[1]; o.z = os[2]; o.w = os[3];
        *(ushort4*)(osc + idx) = o;
    }
}

// ---------------- GEMM2: out = 0.05*tanh(osc@Wr^T + br) + x ----------------
__global__ __launch_bounds__(512, 2) void gemm2_kernel(const u16* __restrict__ A,
                                                       const u16* __restrict__ Bm,
                                                       const float* __restrict__ bias,
                                                       const float* __restrict__ resid,
                                                       float* __restrict__ out_f) {
    __shared__ __align__(16) u16 lds[32768];   // 64 KiB private wave regions
    int flat = blockIdx.y * 8 + blockIdx.x;
    int xcd = flat & 7, p = flat >> 3;
    int tile_m = (xcd * 4 + (p & 3)) * 512;
    int tile_n = (p >> 2) * 128;
    int wave = threadIdx.x >> 6, lane = threadIdx.x & 63;
    f32x4 acc[4][8] = {};
    gemm_wave_core(A, Bm, tile_m, tile_n, lds + wave * 4096, acc);

    int q = lane >> 4, l = lane & 15;
    #pragma unroll
    for (int mi = 0; mi < 4; mi++) {
        #pragma unroll
        for (int r = 0; r < 4; r++) {
            int row = tile_m + wave * 64 + mi * 16 + q * 4 + r;
            #pragma unroll
            for (int ni = 0; ni < 8; ni++) {
                int col = tile_n + ni * 16 + l;
                size_t idx = (size_t)row * D_DIM + col;
                float g = fast_tanh(acc[mi][ni][r] + bias[col]);
                out_f[idx] = 0.05f * g + resid[idx];
            }
        }
    }
}

extern "C" void kernel_launch(void* const* d_in, const int* in_sizes, int n_in,
                              void* d_out, int out_size, void* d_ws, size_t ws_size,
                              hipStream_t stream) {
    const float* x   = (const float*)d_in[0];
    const float* lnw = (const float*)d_in[1];
    const float* lnb = (const float*)d_in[2];
    const float* Wf  = (const float*)d_in[3];
    const float* bf_ = (const float*)d_in[4];
    const float* Wr  = (const float*)d_in[5];
    const float* br  = (const float*)d_in[6];
    const float* ab  = (const float*)d_in[7];
    const float* bs  = (const float*)d_in[8];
    float* out = (float*)d_out;

    // workspace (76 MB):
    //   xn  : [ 0,32MB) bf16 layernorm out; later overwritten in-place by scan output
    //   la  : [32,64MB) bf16 log(alpha+1e-8) from GEMM1
    //   Wfc : [64,66MB)  Wrc : [66,68MB)
    //   S,Tb,Of,SSp : 4 x 2MB fp32 at [68,76MB)
    char* w = (char*)d_ws;
    u16* xn  = (u16*)w;
    u16* la  = (u16*)(w + (size_t)33554432);
    u16* Wfc = (u16*)(w + (size_t)67108864);
    u16* Wrc = (u16*)(w + (size_t)69206016);
    float* S   = (float*)(w + (size_t)71303168);
    float* Tb  = S  + 524288;
    float* Of  = Tb + 524288;
    float* SSp = Of + 524288;
    u16* osc = xn;

    ln_conv_kernel<<<dim3(2048 + M_DIM / 4), dim3(256), 0, stream>>>(
        x, lnw, lnb, xn, Wf, Wr, Wfc, Wrc);
    gemm1_kernel<<<dim3(D_DIM / 128, M_DIM / 512), dim3(512), 0, stream>>>(
        xn, Wfc, bf_, ab, bs, la, S, Tb);
    scan_combine<<<dim3(B_DIM * 16), dim3(1024), 0, stream>>>(la, S, Tb, Of, SSp);
    scan_final<<<dim3(B_DIM * NCHUNK), dim3(256), 0, stream>>>(la, xn, bs, Of, SSp, osc);
    gemm2_kernel<<<dim3(D_DIM / 128, M_DIM / 512), dim3(512), 0, stream>>>(
        osc, Wrc, br, x, out);
}